// Round 10
// baseline (286.853 us; speedup 1.0000x reference)
//
#include <hip/hip_runtime.h>

#define HWPIX 589824
#define Wdim 768
#define Bdim 4
#define Kdim 16
#define NBINS 2048
#define RANGE_F 16.0f
#define BIN_W (RANGE_F / NBINS)
#define INV_BIN_W (NBINS / RANGE_F)
#define EPSf 1e-6f
#define QCLIP 13.8155106f   /* -log(1e-6): q >= QCLIP  <=>  phi clamps to EPS */

#define Q4 (HWPIX / 4)      // 147456 float4 groups per channel
#define NSB 288             // blocks per batch (both heavy kernels)
#define NBLK (NSB * Bdim)   // 1152 blocks
#define GPI (NSB * 256)     // float4-groups per p-iteration per batch (73728; 2 iters)

// ws float offsets
#define ACC_OFF 0                      // [B][K][5]
#define LOVARR_OFF 724                 // [64]
#define HIST_OFF_F 1024                // uint hist[B*K][2][NBINS]
#define NHIST (Bdim * Kdim * 2 * NBINS)
#define SPART_OFF (HIST_OFF_F + NHIST + 64)        // float [NBLK][80]
#define MPART_OFF (SPART_OFF + NBLK * 80)          // float [NBLK][2]

__global__ __launch_bounds__(256, 4) void k_stats(const float* __restrict__ yp,
                                                  const int* __restrict__ yt,
                                                  float* __restrict__ ws,
                                                  unsigned* __restrict__ hist) {
    int b = blockIdx.y;
    int lane = threadIdx.x & 63;
    int wv = threadIdx.x >> 6;
    __shared__ float lpart[4][80];

    // zero hist + posnh (folded memset; 1152*256 threads >= NHIST+64)
    {
        int gtid = (b * NSB + blockIdx.x) * 256 + threadIdx.x;
        if (gtid < NHIST + 64) hist[gtid] = 0u;
    }

    const float4* bp4 = (const float4*)(yp + (size_t)b * 5 * HWPIX);
    const int4* bt4 = (const int4*)(yt + (size_t)b * HWPIX);
    int g0 = blockIdx.x * 256 + threadIdx.x;
    int g1 = g0 + GPI;
    bool lo = (lane < 32);

    // ---------------- pass 1: count, emb_y, emb_x (acc[48] = k*3+c) --------
    {
        float acc[48];
#pragma unroll
        for (int v = 0; v < 48; ++v) acc[v] = 0.f;

        // hoist all pass-1 loads (6 in flight)
        float4 aoy = bp4[g0], aox = bp4[g0 + Q4];
        int4 at = bt4[g0];
        float4 boy = bp4[g1], box = bp4[g1 + Q4];
        int4 bt = bt4[g1];

#define S1_TILE(voy, vox, vt, gbase)                                          \
        do {                                                                  \
            int hwb = (gbase) * 4;                                            \
            float oy[4] = {voy.x, voy.y, voy.z, voy.w};                       \
            float ox[4] = {vox.x, vox.y, vox.z, vox.w};                       \
            int tt[4] = {vt.x, vt.y, vt.z, vt.w};                             \
            _Pragma("unroll") for (int j = 0; j < 4; ++j) {                   \
                int hw = hwb + j;                                             \
                int h = hw / Wdim;                                            \
                int w = hw - h * Wdim;                                        \
                int own = tt[j] - 1;                                          \
                float vy = (float)h + oy[j];                                  \
                float vx = (float)w + ox[j];                                  \
                _Pragma("unroll") for (int k = 0; k < Kdim; ++k) {            \
                    float m = (own == k) ? 1.0f : 0.0f;                       \
                    acc[k * 3 + 0] += m;                                      \
                    acc[k * 3 + 1] = fmaf(m, vy, acc[k * 3 + 1]);             \
                    acc[k * 3 + 2] = fmaf(m, vx, acc[k * 3 + 2]);             \
                }                                                             \
            }                                                                 \
        } while (0)

        S1_TILE(aoy, aox, at, g0);
        S1_TILE(boy, box, bt, g1);
#undef S1_TILE

        // fold: lo lanes own v 0..23, hi lanes own 24..47
#pragma unroll
        for (int v = 0; v < 24; ++v) {
            float send = lo ? acc[v + 24] : acc[v];
            float got = __shfl_xor(send, 32);
            acc[v] += lo ? got : 0.f;
            acc[v + 24] += lo ? 0.f : got;
        }
#pragma unroll
        for (int v = 0; v < 24; ++v) {
            float x = lo ? acc[v] : acc[v + 24];
#pragma unroll
            for (int o = 16; o >= 1; o >>= 1) x += __shfl_xor(x, o);
            if ((lane & 31) == 0) {
                int vv = lo ? v : v + 24;              // logical 0..47 = k*3+c
                lpart[wv][(vv / 3) * 5 + vv % 3] = x;  // SPART slot k*5+c
            }
        }
    }

    // ---------------- pass 2: sig_y, sig_x (acc[32] = k*2+c) ---------------
    {
        float acc[32];
#pragma unroll
        for (int v = 0; v < 32; ++v) acc[v] = 0.f;

        float4 asy = bp4[g0 + 2 * Q4], asx = bp4[g0 + 3 * Q4];
        int4 at = bt4[g0];
        float4 bsy = bp4[g1 + 2 * Q4], bsx = bp4[g1 + 3 * Q4];
        int4 bt = bt4[g1];

#define S2_TILE(vsy, vsx, vt)                                                 \
        do {                                                                  \
            float sy[4] = {vsy.x, vsy.y, vsy.z, vsy.w};                       \
            float sx[4] = {vsx.x, vsx.y, vsx.z, vsx.w};                       \
            int tt[4] = {vt.x, vt.y, vt.z, vt.w};                             \
            _Pragma("unroll") for (int j = 0; j < 4; ++j) {                   \
                int own = tt[j] - 1;                                          \
                _Pragma("unroll") for (int k = 0; k < Kdim; ++k) {            \
                    float m = (own == k) ? 1.0f : 0.0f;                       \
                    acc[k * 2 + 0] = fmaf(m, sy[j], acc[k * 2 + 0]);          \
                    acc[k * 2 + 1] = fmaf(m, sx[j], acc[k * 2 + 1]);          \
                }                                                             \
            }                                                                 \
        } while (0)

        S2_TILE(asy, asx, at);
        S2_TILE(bsy, bsx, bt);
#undef S2_TILE

#pragma unroll
        for (int v = 0; v < 16; ++v) {
            float send = lo ? acc[v + 16] : acc[v];
            float got = __shfl_xor(send, 32);
            acc[v] += lo ? got : 0.f;
            acc[v + 16] += lo ? 0.f : got;
        }
#pragma unroll
        for (int v = 0; v < 16; ++v) {
            float x = lo ? acc[v] : acc[v + 16];
#pragma unroll
            for (int o = 16; o >= 1; o >>= 1) x += __shfl_xor(x, o);
            if ((lane & 31) == 0) {
                int vv = lo ? v : v + 16;                  // logical 0..31 = k*2+c
                lpart[wv][(vv / 2) * 5 + 3 + (vv & 1)] = x;  // slot k*5+3+c
            }
        }
    }

    __syncthreads();
    if (threadIdx.x < 80) {
        float v = lpart[0][threadIdx.x] + lpart[1][threadIdx.x] +
                  lpart[2][threadIdx.x] + lpart[3][threadIdx.x];
        ws[SPART_OFF + (size_t)(b * NSB + blockIdx.x) * 80 + threadIdx.x] = v;
    }
}

// 80 blocks x 256: one wave per output (320 outputs); lane strided-sums the
// NSB partials, butterfly-reduces, lane 0 stores ACC.
__global__ void k_centers2(float* __restrict__ ws) {
    int wv = threadIdx.x >> 6;
    int lane = threadIdx.x & 63;
    int gw = blockIdx.x * 4 + wv;        // 0..319
    int b = gw / 80, idx = gw - b * 80;
    const float* sp = ws + SPART_OFF + (size_t)b * NSB * 80 + idx;
    float x = 0.f;
    for (int j = lane; j < NSB; j += 64) x += sp[(size_t)j * 80];
#pragma unroll
    for (int o = 32; o >= 1; o >>= 1) x += __shfl_xor(x, o);
    if (lane == 0) ws[ACC_OFF + b * 80 + idx] = x;
}

__global__ __launch_bounds__(256, 4) void k_main(const float* __restrict__ yp,
                                                 const int* __restrict__ yt,
                                                 float* __restrict__ ws,
                                                 unsigned* __restrict__ hist) {
    int b = blockIdx.y;
    int lane = threadIdx.x & 63;
    int wv = threadIdx.x >> 6;
    __shared__ float ck_s[32];
    __shared__ float4 msw_s[17];
    __shared__ float part[4][2];
    // prologue: centers/means/weights for this batch from ACC
    if (threadIdx.x < 16) {
        int k = threadIdx.x;
        const float* a = ws + ACC_OFF + (size_t)b * 80 + k * 5;
        float cnt = a[0];
        float safe = fmaxf(cnt, 1.0f);
        float inv = 1.0f / safe;
        ck_s[k * 2 + 0] = a[1] * inv;
        ck_s[k * 2 + 1] = a[2] * inv;
        float4 mw;
        mw.x = a[3] * inv;
        mw.y = a[4] * inv;
        mw.z = (cnt > 0.f) ? 0.5f / cnt : 0.f;
        mw.w = 0.f;
        msw_s[k] = mw;
    }
    if (threadIdx.x == 16) msw_s[16] = (float4){0.f, 0.f, 0.f, 0.f};
    __syncthreads();

    float cky[Kdim], ckx[Kdim];
#pragma unroll
    for (int k = 0; k < Kdim; ++k) {
        cky[k] = ck_s[k * 2];
        ckx[k] = ck_s[k * 2 + 1];
    }

    unsigned* hb = hist + (size_t)(b * Kdim) * 2 * NBINS;
    unsigned* posnh = hist + (size_t)NHIST;
    const float4* bp4 = (const float4*)(yp + (size_t)b * 5 * HWPIX);
    const int4* bt4 = (const int4*)(yt + (size_t)b * HWPIX);
    int g0 = blockIdx.x * 256 + threadIdx.x;
    int g1 = g0 + GPI;

    // hoist ALL loads (12 in flight)
    float4 aoy = bp4[g0], aox = bp4[g0 + Q4], asy = bp4[g0 + 2 * Q4];
    float4 asx = bp4[g0 + 3 * Q4], ase = bp4[g0 + 4 * Q4];
    int4 at = bt4[g0];
    float4 boy = bp4[g1], box = bp4[g1 + Q4], bsy = bp4[g1 + 2 * Q4];
    float4 bsx = bp4[g1 + 3 * Q4], bse = bp4[g1 + 4 * Q4];
    int4 btt = bt4[g1];

    float varsum = 0.f, ssum = 0.f;

#define M_TILE(voy, vox, vsy, vsx, vse, vt, gbase)                            \
    do {                                                                      \
        int hwb = (gbase) * 4;                                                \
        float oy[4] = {voy.x, voy.y, voy.z, voy.w};                           \
        float ox[4] = {vox.x, vox.y, vox.z, vox.w};                           \
        float sya[4] = {vsy.x, vsy.y, vsy.z, vsy.w};                          \
        float sxa[4] = {vsx.x, vsx.y, vsx.z, vsx.w};                          \
        float sea[4] = {vse.x, vse.y, vse.z, vse.w};                          \
        int tt[4] = {vt.x, vt.y, vt.z, vt.w};                                 \
        _Pragma("unroll") for (int j = 0; j < 4; ++j) {                       \
            int hw = hwb + j;                                                 \
            int h = hw / Wdim;                                                \
            int w = hw - h * Wdim;                                            \
            int own = tt[j] - 1;                                              \
            float sy = sya[j], sx = sxa[j];                                   \
            float ey = (float)h + oy[j], ex = (float)w + ox[j];               \
            float sby = fmaxf(sy, EPSf), sbx = fmaxf(sx, EPSf);               \
            float iy = 0.5f / (sby * sby), ix = 0.5f / (sbx * sbx);           \
            unsigned sm = 0;                                                  \
            _Pragma("unroll") for (int k = 0; k < Kdim; ++k) {                \
                float dy = ey - cky[k];                                       \
                float dx = ex - ckx[k];                                       \
                float q = fmaf(dy * dy, iy, dx * dx * ix);                    \
                if (q < QCLIP) sm |= (1u << k);                               \
            }                                                                 \
            int ow = (own >= 0) ? own : 16;                                   \
            float4 mw = msw_s[ow];                                            \
            float devv = fabsf(sy - mw.x) + fabsf(sx - mw.y);                 \
            varsum = fmaf(devv, mw.z, varsum);                                \
            float st = (own >= 0) ? EPSf : 0.f;                               \
            while (sm) {                                                      \
                int k = __ffs(sm) - 1;                                        \
                sm &= sm - 1;                                                 \
                float dy = ey - ck_s[k * 2];                                  \
                float dx = ex - ck_s[k * 2 + 1];                              \
                float q = fmaf(dy * dy, iy, dx * dx * ix);                    \
                float phi = expf(-q);                                         \
                phi = fminf(fmaxf(phi, EPSf), 1.0f - EPSf);                   \
                float lg = logf(phi) - log1pf(-phi);                          \
                bool isPos = (k == own);                                      \
                float e;                                                      \
                if (isPos) {                                                  \
                    st = phi;                                                 \
                    atomicAdd(&posnh[b * Kdim + k], 1u);                      \
                    e = 1.0f - lg;                                            \
                } else {                                                      \
                    e = 1.0f + lg;                                            \
                }                                                             \
                if (e > 0.f) {                                                \
                    int bin = (int)(e * INV_BIN_W);                           \
                    if (bin > NBINS - 1) bin = NBINS - 1;                     \
                    atomicAdd(&hb[(k * 2 + (isPos ? 1 : 0)) * NBINS + bin], 1u); \
                }                                                             \
            }                                                                 \
            float dd = sea[j] - st;                                           \
            ssum = fmaf(dd, dd, ssum);                                        \
        }                                                                     \
    } while (0)

    M_TILE(aoy, aox, asy, asx, ase, at, g0);
    M_TILE(boy, box, bsy, bsx, bse, btt, g1);
#undef M_TILE

#pragma unroll
    for (int o = 32; o >= 1; o >>= 1) {
        varsum += __shfl_xor(varsum, o);
        ssum += __shfl_xor(ssum, o);
    }
    if (lane == 0) {
        part[wv][0] = varsum;
        part[wv][1] = ssum;
    }
    __syncthreads();
    if (threadIdx.x < 2) {
        float v = part[0][threadIdx.x] + part[1][threadIdx.x] +
                  part[2][threadIdx.x] + part[3][threadIdx.x];
        ws[MPART_OFF + (size_t)(b * NSB + blockIdx.x) * 2 + threadIdx.x] = v;
    }
}

// One wave per (b,k): suffix-scan histogram top-down, trapezoid-integrate
// J(t) = 1 - (P - p(t))/(P + n(t)).  Clamped positives enter implicitly as
// deficit = P - posnh at HOTBIN.
__global__ void k_lovasz(float* __restrict__ ws, const unsigned* __restrict__ hist) {
    int i = blockIdx.x;  // 0..63
    int lane = threadIdx.x;
    float P = ws[ACC_OFF + i * 5];
    if (P < 0.5f) {
        if (lane == 0) ws[LOVARR_OFF + i] = 0.f;
        return;
    }
    const unsigned* hn = hist + (size_t)i * 2 * NBINS;
    const unsigned* hp = hn + NBINS;
    const unsigned* posnh = hist + (size_t)NHIST;
    const float C_LO = logf(EPSf) - log1pf(-EPSf);
    const int HOTBIN = (int)((1.0f - C_LO) * INV_BIN_W);
    int deficit = (int)(P + 0.5f) - (int)posnh[i];
    int carry_p = 0, carry_n = 0;
    float Jtop = 0.f;
    float trap = 0.f;
    for (int c = NBINS / 64 - 1; c >= 0; --c) {
        int m = c * 64 + lane;
        int vp = (int)hp[m];
        int vn = (int)hn[m];
        if (m == HOTBIN) vp += deficit;
        for (int o = 1; o < 64; o <<= 1) {
            int tp = __shfl_down(vp, o);
            int tn = __shfl_down(vn, o);
            if (lane + o < 64) { vp += tp; vn += tn; }
        }
        float p_edge = (float)(carry_p + vp);
        float n_edge = (float)(carry_n + vn);
        float J = 1.0f - (P - p_edge) / (P + n_edge);
        float Jn = __shfl_down(J, 1);
        if (lane == 63) Jn = Jtop;
        trap += 0.5f * (J + Jn);
        carry_p += __shfl(vp, 0);
        carry_n += __shfl(vn, 0);
        Jtop = __shfl(J, 0);
    }
    for (int o = 1; o < 64; o <<= 1) {
        float t2 = __shfl_down(trap, o);
        if (lane + o < 64) trap += t2;
    }
    if (lane == 0) ws[LOVARR_OFF + i] = trap * BIN_W;
}

__global__ void k_final(const float* __restrict__ ws, float* __restrict__ out) {
    __shared__ float r0[256], r1[256], r2[256], r3[256];
    int t = threadIdx.x;
    float v = 0.f, s = 0.f, l = 0.f, pr = 0.f;
    for (int j = t; j < NBLK; j += 256) {
        v += ws[MPART_OFF + 2 * j];
        s += ws[MPART_OFF + 2 * j + 1];
    }
    if (t < 64) {
        l = ws[LOVARR_OFF + t];
        pr = (ws[ACC_OFF + t * 5] > 0.f) ? 1.f : 0.f;
    }
    r0[t] = v; r1[t] = s; r2[t] = l; r3[t] = pr;
    __syncthreads();
    for (int o = 128; o > 0; o >>= 1) {
        if (t < o) {
            r0[t] += r0[t + o]; r1[t] += r1[t + o];
            r2[t] += r2[t + o]; r3[t] += r3[t + o];
        }
        __syncthreads();
    }
    if (t == 0) {
        float npres = fmaxf(r3[0], 1.0f);
        out[0] = r2[0] / npres + 10.0f * (r0[0] / npres) +
                 r1[0] / (float)((size_t)Bdim * HWPIX);
    }
}

extern "C" void kernel_launch(void* const* d_in, const int* in_sizes, int n_in,
                              void* d_out, int out_size, void* d_ws, size_t ws_size,
                              hipStream_t stream) {
    const float* yp = (const float*)d_in[0];
    const int* yt = (const int*)d_in[1];
    float* ws = (float*)d_ws;
    unsigned* hist = (unsigned*)((char*)d_ws + HIST_OFF_F * 4);

    dim3 g(NSB, Bdim);
    k_stats<<<g, 256, 0, stream>>>(yp, yt, ws, hist);
    k_centers2<<<80, 256, 0, stream>>>(ws);
    k_main<<<g, 256, 0, stream>>>(yp, yt, ws, hist);
    k_lovasz<<<64, 64, 0, stream>>>(ws, hist);
    k_final<<<1, 256, 0, stream>>>(ws, (float*)d_out);
}

// Round 11
// 117.086 us; speedup vs baseline: 2.4499x; 2.4499x over previous
//
#include <hip/hip_runtime.h>

#define HWPIX 589824
#define Wdim 768
#define Bdim 4
#define Kdim 16
#define NBINS 2048
#define RANGE_F 16.0f
#define BIN_W (RANGE_F / NBINS)
#define INV_BIN_W (NBINS / RANGE_F)
#define EPSf 1e-6f
#define QCLIP 13.8155106f   /* -log(1e-6): q >= QCLIP  <=>  phi clamps to EPS */

#define Q4 (HWPIX / 4)      // 147456 float4 groups per channel
#define NSB 288             // blocks per batch
#define NBLK (NSB * Bdim)   // 1152 blocks
#define GPI (NSB * 256)     // 73728 groups per tile-pass (2 passes cover Q4)

// ws float offsets
#define ACC_OFF 0                      // [B][K][5]
#define LOVARR_OFF 724                 // [64]
#define HIST_OFF_F 1024                // uint hist[B*K][2][NBINS]
#define NHIST (Bdim * Kdim * 2 * NBINS)
#define SPART_OFF (HIST_OFF_F + NHIST + 64)        // float [NBLK][80]
#define MPART_OFF (SPART_OFF + NBLK * 80)          // float [NBLK][2]

// ---------------- stats pass 1: count + emb sums (slots k*5+{0,1,2}) --------
__global__ __launch_bounds__(256, 4) void k_statsE(const float* __restrict__ yp,
                                                   const int* __restrict__ yt,
                                                   float* __restrict__ ws,
                                                   unsigned* __restrict__ hist) {
    int b = blockIdx.y;
    int lane = threadIdx.x & 63;
    int wv = threadIdx.x >> 6;
    __shared__ float lpart[4][48];

    // zero hist + posnh (1152*256 = 294912 threads >= NHIST+64)
    {
        int gtid = (b * NSB + blockIdx.x) * 256 + threadIdx.x;
        if (gtid < NHIST + 64) hist[gtid] = 0u;
    }

    const float4* bp4 = (const float4*)(yp + (size_t)b * 5 * HWPIX);
    const int4* bt4 = (const int4*)(yt + (size_t)b * HWPIX);
    int g0 = blockIdx.x * 256 + threadIdx.x;
    int g1 = g0 + GPI;

    // hoist all loads (6 in flight)
    float4 aoy = bp4[g0], aox = bp4[g0 + Q4];
    int4 ait = bt4[g0];
    float4 boy = bp4[g1], box = bp4[g1 + Q4];
    int4 bit = bt4[g1];

    float acc[48];
#pragma unroll
    for (int v = 0; v < 48; ++v) acc[v] = 0.f;

    auto tile = [&](const float4& voy, const float4& vox, const int4& vt,
                    int gbase) {
        float oy[4] = {voy.x, voy.y, voy.z, voy.w};
        float ox[4] = {vox.x, vox.y, vox.z, vox.w};
        int tt[4] = {vt.x, vt.y, vt.z, vt.w};
        int hwb = gbase * 4;
#pragma unroll
        for (int j = 0; j < 4; ++j) {
            int hw = hwb + j;
            int h = hw / Wdim;
            int w = hw - h * Wdim;
            int own = tt[j] - 1;
            float vy = (float)h + oy[j];
            float vx = (float)w + ox[j];
#pragma unroll
            for (int k = 0; k < Kdim; ++k) {
                float m = (own == k) ? 1.0f : 0.0f;
                acc[k * 3 + 0] += m;
                acc[k * 3 + 1] = fmaf(m, vy, acc[k * 3 + 1]);
                acc[k * 3 + 2] = fmaf(m, vx, acc[k * 3 + 2]);
            }
        }
    };
    tile(aoy, aox, ait, g0);
    tile(boy, box, bit, g1);

    bool lo = (lane < 32);
#pragma unroll
    for (int v = 0; v < 24; ++v) {
        float send = lo ? acc[v + 24] : acc[v];
        float got = __shfl_xor(send, 32);
        acc[v] += lo ? got : 0.f;
        acc[v + 24] += lo ? 0.f : got;
    }
#pragma unroll
    for (int v = 0; v < 24; ++v) {
        float x = lo ? acc[v] : acc[v + 24];
#pragma unroll
        for (int o = 16; o >= 1; o >>= 1) x += __shfl_xor(x, o);
        if ((lane & 31) == 0) lpart[wv][lo ? v : v + 24] = x;
    }
    __syncthreads();
    if (threadIdx.x < 48) {
        float v = lpart[0][threadIdx.x] + lpart[1][threadIdx.x] +
                  lpart[2][threadIdx.x] + lpart[3][threadIdx.x];
        int slot = (threadIdx.x / 3) * 5 + threadIdx.x % 3;
        ws[SPART_OFF + (size_t)(b * NSB + blockIdx.x) * 80 + slot] = v;
    }
}

// ---------------- stats pass 2: sig sums (slots k*5+{3,4}) ------------------
__global__ __launch_bounds__(256, 4) void k_statsS(const float* __restrict__ yp,
                                                   const int* __restrict__ yt,
                                                   float* __restrict__ ws) {
    int b = blockIdx.y;
    int lane = threadIdx.x & 63;
    int wv = threadIdx.x >> 6;
    __shared__ float lpart[4][32];

    const float4* bp4 = (const float4*)(yp + (size_t)b * 5 * HWPIX);
    const int4* bt4 = (const int4*)(yt + (size_t)b * HWPIX);
    int g0 = blockIdx.x * 256 + threadIdx.x;
    int g1 = g0 + GPI;

    float4 asy = bp4[g0 + 2 * Q4], asx = bp4[g0 + 3 * Q4];
    int4 ait = bt4[g0];
    float4 bsy = bp4[g1 + 2 * Q4], bsx = bp4[g1 + 3 * Q4];
    int4 bit = bt4[g1];

    float acc[32];
#pragma unroll
    for (int v = 0; v < 32; ++v) acc[v] = 0.f;

    auto tile = [&](const float4& vsy, const float4& vsx, const int4& vt) {
        float sy[4] = {vsy.x, vsy.y, vsy.z, vsy.w};
        float sx[4] = {vsx.x, vsx.y, vsx.z, vsx.w};
        int tt[4] = {vt.x, vt.y, vt.z, vt.w};
#pragma unroll
        for (int j = 0; j < 4; ++j) {
            int own = tt[j] - 1;
#pragma unroll
            for (int k = 0; k < Kdim; ++k) {
                float m = (own == k) ? 1.0f : 0.0f;
                acc[k * 2 + 0] = fmaf(m, sy[j], acc[k * 2 + 0]);
                acc[k * 2 + 1] = fmaf(m, sx[j], acc[k * 2 + 1]);
            }
        }
    };
    tile(asy, asx, ait);
    tile(bsy, bsx, bit);

    bool lo = (lane < 32);
#pragma unroll
    for (int v = 0; v < 16; ++v) {
        float send = lo ? acc[v + 16] : acc[v];
        float got = __shfl_xor(send, 32);
        acc[v] += lo ? got : 0.f;
        acc[v + 16] += lo ? 0.f : got;
    }
#pragma unroll
    for (int v = 0; v < 16; ++v) {
        float x = lo ? acc[v] : acc[v + 16];
#pragma unroll
        for (int o = 16; o >= 1; o >>= 1) x += __shfl_xor(x, o);
        if ((lane & 31) == 0) lpart[wv][lo ? v : v + 16] = x;
    }
    __syncthreads();
    if (threadIdx.x < 32) {
        float v = lpart[0][threadIdx.x] + lpart[1][threadIdx.x] +
                  lpart[2][threadIdx.x] + lpart[3][threadIdx.x];
        int slot = (threadIdx.x / 2) * 5 + 3 + (threadIdx.x & 1);
        ws[SPART_OFF + (size_t)(b * NSB + blockIdx.x) * 80 + slot] = v;
    }
}

// 80 blocks x 256: one wave per output (320 outputs)
__global__ void k_centers2(float* __restrict__ ws) {
    int wv = threadIdx.x >> 6;
    int lane = threadIdx.x & 63;
    int gw = blockIdx.x * 4 + wv;        // 0..319
    int b = gw / 80, idx = gw - b * 80;
    const float* sp = ws + SPART_OFF + (size_t)b * NSB * 80 + idx;
    float x = 0.f;
    for (int j = lane; j < NSB; j += 64) x += sp[(size_t)j * 80];
#pragma unroll
    for (int o = 32; o >= 1; o >>= 1) x += __shfl_xor(x, o);
    if (lane == 0) ws[ACC_OFF + b * 80 + idx] = x;
}

__global__ __launch_bounds__(256, 4) void k_main(const float* __restrict__ yp,
                                                 const int* __restrict__ yt,
                                                 float* __restrict__ ws,
                                                 unsigned* __restrict__ hist) {
    int b = blockIdx.y;
    int lane = threadIdx.x & 63;
    int wv = threadIdx.x >> 6;
    __shared__ float ck_s[32];
    __shared__ float4 msw_s[17];
    __shared__ float part[4][2];
    if (threadIdx.x < 16) {
        int k = threadIdx.x;
        const float* a = ws + ACC_OFF + (size_t)b * 80 + k * 5;
        float cnt = a[0];
        float safe = fmaxf(cnt, 1.0f);
        float inv = 1.0f / safe;
        ck_s[k * 2 + 0] = a[1] * inv;
        ck_s[k * 2 + 1] = a[2] * inv;
        float4 mw;
        mw.x = a[3] * inv;
        mw.y = a[4] * inv;
        mw.z = (cnt > 0.f) ? 0.5f / cnt : 0.f;
        mw.w = 0.f;
        msw_s[k] = mw;
    }
    if (threadIdx.x == 16) msw_s[16] = (float4){0.f, 0.f, 0.f, 0.f};
    __syncthreads();

    float cky[Kdim], ckx[Kdim];
#pragma unroll
    for (int k = 0; k < Kdim; ++k) {
        cky[k] = ck_s[k * 2];
        ckx[k] = ck_s[k * 2 + 1];
    }

    unsigned* hb = hist + (size_t)(b * Kdim) * 2 * NBINS;
    unsigned* posnh = hist + (size_t)NHIST;
    const float4* bp4 = (const float4*)(yp + (size_t)b * 5 * HWPIX);
    const int4* bt4 = (const int4*)(yt + (size_t)b * HWPIX);
    int g0 = blockIdx.x * 256 + threadIdx.x;
    int g1 = g0 + GPI;

    // hoist all 12 loads
    float4 aoy = bp4[g0], aox = bp4[g0 + Q4], asy = bp4[g0 + 2 * Q4];
    float4 asx = bp4[g0 + 3 * Q4], ase = bp4[g0 + 4 * Q4];
    int4 ait = bt4[g0];
    float4 boy = bp4[g1], box = bp4[g1 + Q4], bsy = bp4[g1 + 2 * Q4];
    float4 bsx = bp4[g1 + 3 * Q4], bse = bp4[g1 + 4 * Q4];
    int4 bit = bt4[g1];

    float varsum = 0.f, ssum = 0.f;

    auto tile = [&](const float4& voy, const float4& vox, const float4& vsy,
                    const float4& vsx, const float4& vse, const int4& vt,
                    int gbase) {
        float oy[4] = {voy.x, voy.y, voy.z, voy.w};
        float ox[4] = {vox.x, vox.y, vox.z, vox.w};
        float sya[4] = {vsy.x, vsy.y, vsy.z, vsy.w};
        float sxa[4] = {vsx.x, vsx.y, vsx.z, vsx.w};
        float sea[4] = {vse.x, vse.y, vse.z, vse.w};
        int tt[4] = {vt.x, vt.y, vt.z, vt.w};
        int hwb = gbase * 4;
#pragma unroll
        for (int j = 0; j < 4; ++j) {
            int hw = hwb + j;
            int h = hw / Wdim;
            int w = hw - h * Wdim;
            int own = tt[j] - 1;
            float sy = sya[j], sx = sxa[j];
            float ey = (float)h + oy[j], ex = (float)w + ox[j];
            float sby = fmaxf(sy, EPSf), sbx = fmaxf(sx, EPSf);
            float iy = 0.5f / (sby * sby), ix = 0.5f / (sbx * sbx);

            unsigned sm = 0;
#pragma unroll
            for (int k = 0; k < Kdim; ++k) {
                float dy = ey - cky[k];
                float dx = ex - ckx[k];
                float q = fmaf(dy * dy, iy, dx * dx * ix);
                if (q < QCLIP) sm |= (1u << k);
            }
            int ow = (own >= 0) ? own : 16;
            float4 mw = msw_s[ow];
            float devv = fabsf(sy - mw.x) + fabsf(sx - mw.y);
            varsum = fmaf(devv, mw.z, varsum);

            float st = (own >= 0) ? EPSf : 0.f;
            while (sm) {  // rare slow path: near some center
                int k = __ffs(sm) - 1;
                sm &= sm - 1;
                float dy = ey - ck_s[k * 2];
                float dx = ex - ck_s[k * 2 + 1];
                float q = fmaf(dy * dy, iy, dx * dx * ix);
                float phi = expf(-q);
                phi = fminf(fmaxf(phi, EPSf), 1.0f - EPSf);
                float lg = logf(phi) - log1pf(-phi);
                bool isPos = (k == own);
                float e;
                if (isPos) {
                    st = phi;
                    atomicAdd(&posnh[b * Kdim + k], 1u);
                    e = 1.0f - lg;
                } else {
                    e = 1.0f + lg;
                }
                if (e > 0.f) {
                    int bin = (int)(e * INV_BIN_W);
                    if (bin > NBINS - 1) bin = NBINS - 1;
                    atomicAdd(&hb[(k * 2 + (isPos ? 1 : 0)) * NBINS + bin], 1u);
                }
            }
            float dd = sea[j] - st;
            ssum = fmaf(dd, dd, ssum);
        }
    };
    tile(aoy, aox, asy, asx, ase, ait, g0);
    tile(boy, box, bsy, bsx, bse, bit, g1);

#pragma unroll
    for (int o = 32; o >= 1; o >>= 1) {
        varsum += __shfl_xor(varsum, o);
        ssum += __shfl_xor(ssum, o);
    }
    if (lane == 0) {
        part[wv][0] = varsum;
        part[wv][1] = ssum;
    }
    __syncthreads();
    if (threadIdx.x < 2) {
        float v = part[0][threadIdx.x] + part[1][threadIdx.x] +
                  part[2][threadIdx.x] + part[3][threadIdx.x];
        ws[MPART_OFF + (size_t)(b * NSB + blockIdx.x) * 2 + threadIdx.x] = v;
    }
}

// One wave per (b,k): suffix-scan histogram top-down, trapezoid-integrate.
__global__ void k_lovasz(float* __restrict__ ws, const unsigned* __restrict__ hist) {
    int i = blockIdx.x;  // 0..63
    int lane = threadIdx.x;
    float P = ws[ACC_OFF + i * 5];
    if (P < 0.5f) {
        if (lane == 0) ws[LOVARR_OFF + i] = 0.f;
        return;
    }
    const unsigned* hn = hist + (size_t)i * 2 * NBINS;
    const unsigned* hp = hn + NBINS;
    const unsigned* posnh = hist + (size_t)NHIST;
    const float C_LO = logf(EPSf) - log1pf(-EPSf);
    const int HOTBIN = (int)((1.0f - C_LO) * INV_BIN_W);
    int deficit = (int)(P + 0.5f) - (int)posnh[i];
    int carry_p = 0, carry_n = 0;
    float Jtop = 0.f;
    float trap = 0.f;
    for (int c = NBINS / 64 - 1; c >= 0; --c) {
        int m = c * 64 + lane;
        int vp = (int)hp[m];
        int vn = (int)hn[m];
        if (m == HOTBIN) vp += deficit;
        for (int o = 1; o < 64; o <<= 1) {
            int tp = __shfl_down(vp, o);
            int tn = __shfl_down(vn, o);
            if (lane + o < 64) { vp += tp; vn += tn; }
        }
        float p_edge = (float)(carry_p + vp);
        float n_edge = (float)(carry_n + vn);
        float J = 1.0f - (P - p_edge) / (P + n_edge);
        float Jn = __shfl_down(J, 1);
        if (lane == 63) Jn = Jtop;
        trap += 0.5f * (J + Jn);
        carry_p += __shfl(vp, 0);
        carry_n += __shfl(vn, 0);
        Jtop = __shfl(J, 0);
    }
    for (int o = 1; o < 64; o <<= 1) {
        float t2 = __shfl_down(trap, o);
        if (lane + o < 64) trap += t2;
    }
    if (lane == 0) ws[LOVARR_OFF + i] = trap * BIN_W;
}

__global__ void k_final(const float* __restrict__ ws, float* __restrict__ out) {
    __shared__ float r0[256], r1[256], r2[256], r3[256];
    int t = threadIdx.x;
    float v = 0.f, s = 0.f, l = 0.f, pr = 0.f;
    for (int j = t; j < NBLK; j += 256) {
        v += ws[MPART_OFF + 2 * j];
        s += ws[MPART_OFF + 2 * j + 1];
    }
    if (t < 64) {
        l = ws[LOVARR_OFF + t];
        pr = (ws[ACC_OFF + t * 5] > 0.f) ? 1.f : 0.f;
    }
    r0[t] = v; r1[t] = s; r2[t] = l; r3[t] = pr;
    __syncthreads();
    for (int o = 128; o > 0; o >>= 1) {
        if (t < o) {
            r0[t] += r0[t + o]; r1[t] += r1[t + o];
            r2[t] += r2[t + o]; r3[t] += r3[t + o];
        }
        __syncthreads();
    }
    if (t == 0) {
        float npres = fmaxf(r3[0], 1.0f);
        out[0] = r2[0] / npres + 10.0f * (r0[0] / npres) +
                 r1[0] / (float)((size_t)Bdim * HWPIX);
    }
}

extern "C" void kernel_launch(void* const* d_in, const int* in_sizes, int n_in,
                              void* d_out, int out_size, void* d_ws, size_t ws_size,
                              hipStream_t stream) {
    const float* yp = (const float*)d_in[0];
    const int* yt = (const int*)d_in[1];
    float* ws = (float*)d_ws;
    unsigned* hist = (unsigned*)((char*)d_ws + HIST_OFF_F * 4);

    dim3 g(NSB, Bdim);
    k_statsE<<<g, 256, 0, stream>>>(yp, yt, ws, hist);
    k_statsS<<<g, 256, 0, stream>>>(yp, yt, ws);
    k_centers2<<<80, 256, 0, stream>>>(ws);
    k_main<<<g, 256, 0, stream>>>(yp, yt, ws, hist);
    k_lovasz<<<64, 64, 0, stream>>>(ws, hist);
    k_final<<<1, 256, 0, stream>>>(ws, (float*)d_out);
}

// Round 12
// 86.181 us; speedup vs baseline: 3.3285x; 1.3586x over previous
//
#include <hip/hip_runtime.h>

#define HWPIX 589824
#define Wdim 768
#define Bdim 4
#define Kdim 16
#define NBINS 2048
#define RANGE_F 16.0f
#define BIN_W (RANGE_F / NBINS)
#define INV_BIN_W (NBINS / RANGE_F)
#define EPSf 1e-6f
#define QCLIP 13.8155106f   /* -log(1e-6): q >= QCLIP  <=>  phi clamps to EPS */

#define Q4 (HWPIX / 4)      // 147456 float4 groups per channel
#define NSB 192             // blocks per batch
#define NBLK (NSB * Bdim)   // 768 blocks
#define GPI (NSB * 256)     // float4-groups per p-iteration per batch (3 iters)

// ws float offsets
#define ACC_OFF 0                      // [B][K][5]
#define LOVARR_OFF 724                 // [64]
#define HIST_OFF_F 1024                // uint hist[B*K][2][NBINS]
#define NHIST (Bdim * Kdim * 2 * NBINS)
// hist tail: [NHIST..NHIST+63] = posnh, [NHIST+64] = completion counter
#define HTAIL 80
#define SPART_OFF (HIST_OFF_F + NHIST + 128)       // float [NBLK][80]
#define MPART_OFF (SPART_OFF + NBLK * 80)          // float [NBLK][2]

__global__ __launch_bounds__(256, 3) void k_stats(const float* __restrict__ yp,
                                                  const int* __restrict__ yt,
                                                  float* __restrict__ ws,
                                                  unsigned* __restrict__ hist) {
    int b = blockIdx.y;
    int lane = threadIdx.x & 63;
    int wv = threadIdx.x >> 6;
    __shared__ float lpart[4][80];

    // zero hist + posnh + counter (folded memset)
    {
        int gtid = (b * NSB + blockIdx.x) * 256 + threadIdx.x;
        for (int i = gtid; i < NHIST + HTAIL; i += NBLK * 256) hist[i] = 0u;
    }

    const float4* bp4 = (const float4*)(yp + (size_t)b * 5 * HWPIX);
    const int4* bt4 = (const int4*)(yt + (size_t)b * HWPIX);

    float acc[80];
#pragma unroll
    for (int v = 0; v < 80; ++v) acc[v] = 0.f;

    int g = blockIdx.x * 256 + threadIdx.x;
    // stage 0 loads
    float4 coy = bp4[g], cox = bp4[g + Q4];
    float4 csy = bp4[g + 2 * Q4], csx = bp4[g + 3 * Q4];
    int4 ct = bt4[g];

#pragma unroll
    for (int p = 0; p < 3; ++p) {
        // prefetch next iteration before consuming current
        float4 noy, nox, nsy, nsx;
        int4 nt_;
        if (p < 2) {
            int gn = g + GPI;
            noy = bp4[gn];
            nox = bp4[gn + Q4];
            nsy = bp4[gn + 2 * Q4];
            nsx = bp4[gn + 3 * Q4];
            nt_ = bt4[gn];
        }
        {
            int hwb = g * 4;
            float oy[4] = {coy.x, coy.y, coy.z, coy.w};
            float ox[4] = {cox.x, cox.y, cox.z, cox.w};
            float sy[4] = {csy.x, csy.y, csy.z, csy.w};
            float sx[4] = {csx.x, csx.y, csx.z, csx.w};
            int tt[4] = {ct.x, ct.y, ct.z, ct.w};
#pragma unroll
            for (int j = 0; j < 4; ++j) {
                int hw = hwb + j;
                int h = hw / Wdim;
                int w = hw - h * Wdim;
                int own = tt[j] - 1;
                float vy = (float)h + oy[j];
                float vx = (float)w + ox[j];
#pragma unroll
                for (int k = 0; k < Kdim; ++k) {
                    float m = (own == k) ? 1.0f : 0.0f;
                    acc[k * 5 + 0] += m;
                    acc[k * 5 + 1] = fmaf(m, vy, acc[k * 5 + 1]);
                    acc[k * 5 + 2] = fmaf(m, vx, acc[k * 5 + 2]);
                    acc[k * 5 + 3] = fmaf(m, sy[j], acc[k * 5 + 3]);
                    acc[k * 5 + 4] = fmaf(m, sx[j], acc[k * 5 + 4]);
                }
            }
        }
        if (p < 2) {
            coy = noy; cox = nox; csy = nsy; csx = nsx; ct = nt_;
            g += GPI;
        }
    }

    // fold across half-waves: lanes 0-31 own values 0..39, lanes 32-63 own 40..79
    bool lo = (lane < 32);
#pragma unroll
    for (int v = 0; v < 40; ++v) {
        float send = lo ? acc[v + 40] : acc[v];
        float got = __shfl_xor(send, 32);
        acc[v] += lo ? got : 0.f;
        acc[v + 40] += lo ? 0.f : got;
    }
#pragma unroll
    for (int v = 0; v < 40; ++v) {
        float x = lo ? acc[v] : acc[v + 40];
#pragma unroll
        for (int o = 16; o >= 1; o >>= 1) x += __shfl_xor(x, o);
        if ((lane & 31) == 0) lpart[wv][lo ? v : v + 40] = x;
    }
    __syncthreads();
    if (threadIdx.x < 80) {
        float v = lpart[0][threadIdx.x] + lpart[1][threadIdx.x] +
                  lpart[2][threadIdx.x] + lpart[3][threadIdx.x];
        ws[SPART_OFF + (size_t)(b * NSB + blockIdx.x) * 80 + threadIdx.x] = v;
    }
}

// 80 blocks x 256: one wave per output (320 outputs)
__global__ void k_centers2(float* __restrict__ ws) {
    int wv = threadIdx.x >> 6;
    int lane = threadIdx.x & 63;
    int gw = blockIdx.x * 4 + wv;        // 0..319
    int b = gw / 80, idx = gw - b * 80;
    const float* sp = ws + SPART_OFF + (size_t)b * NSB * 80 + idx;
    float x = sp[(size_t)lane * 80] + sp[(size_t)(lane + 64) * 80] +
              sp[(size_t)(lane + 128) * 80];
#pragma unroll
    for (int o = 32; o >= 1; o >>= 1) x += __shfl_xor(x, o);
    if (lane == 0) ws[ACC_OFF + b * 80 + idx] = x;
}

__global__ __launch_bounds__(256, 3) void k_main(const float* __restrict__ yp,
                                                 const int* __restrict__ yt,
                                                 float* __restrict__ ws,
                                                 unsigned* __restrict__ hist) {
    int b = blockIdx.y;
    int lane = threadIdx.x & 63;
    int wv = threadIdx.x >> 6;
    __shared__ float ck_s[32];
    __shared__ float4 msw_s[17];
    __shared__ float part[4][2];
    if (threadIdx.x < 16) {
        int k = threadIdx.x;
        const float* a = ws + ACC_OFF + (size_t)b * 80 + k * 5;
        float cnt = a[0];
        float safe = fmaxf(cnt, 1.0f);
        float inv = 1.0f / safe;
        ck_s[k * 2 + 0] = a[1] * inv;
        ck_s[k * 2 + 1] = a[2] * inv;
        float4 mw;
        mw.x = a[3] * inv;
        mw.y = a[4] * inv;
        mw.z = (cnt > 0.f) ? 0.5f / cnt : 0.f;
        mw.w = 0.f;
        msw_s[k] = mw;
    }
    if (threadIdx.x == 16) msw_s[16] = (float4){0.f, 0.f, 0.f, 0.f};
    __syncthreads();

    float cky[Kdim], ckx[Kdim];
#pragma unroll
    for (int k = 0; k < Kdim; ++k) {
        cky[k] = ck_s[k * 2];
        ckx[k] = ck_s[k * 2 + 1];
    }

    unsigned* hb = hist + (size_t)(b * Kdim) * 2 * NBINS;
    unsigned* posnh = hist + (size_t)NHIST;
    const float4* bp4 = (const float4*)(yp + (size_t)b * 5 * HWPIX);
    const int4* bt4 = (const int4*)(yt + (size_t)b * HWPIX);

    float varsum = 0.f, ssum = 0.f;
    int g = blockIdx.x * 256 + threadIdx.x;
    // stage 0 loads
    float4 coy = bp4[g], cox = bp4[g + Q4];
    float4 csy = bp4[g + 2 * Q4], csx = bp4[g + 3 * Q4];
    float4 cse = bp4[g + 4 * Q4];
    int4 ct = bt4[g];

#pragma unroll
    for (int p = 0; p < 3; ++p) {
        float4 noy, nox, nsy, nsx, nse;
        int4 nt_;
        if (p < 2) {
            int gn = g + GPI;
            noy = bp4[gn];
            nox = bp4[gn + Q4];
            nsy = bp4[gn + 2 * Q4];
            nsx = bp4[gn + 3 * Q4];
            nse = bp4[gn + 4 * Q4];
            nt_ = bt4[gn];
        }
        {
            int hwb = g * 4;
            float oy[4] = {coy.x, coy.y, coy.z, coy.w};
            float ox[4] = {cox.x, cox.y, cox.z, cox.w};
            float sya[4] = {csy.x, csy.y, csy.z, csy.w};
            float sxa[4] = {csx.x, csx.y, csx.z, csx.w};
            float sea[4] = {cse.x, cse.y, cse.z, cse.w};
            int tt[4] = {ct.x, ct.y, ct.z, ct.w};
#pragma unroll
            for (int j = 0; j < 4; ++j) {
                int hw = hwb + j;
                int h = hw / Wdim;
                int w = hw - h * Wdim;
                int own = tt[j] - 1;
                float sy = sya[j], sx = sxa[j];
                float ey = (float)h + oy[j], ex = (float)w + ox[j];
                float sby = fmaxf(sy, EPSf), sbx = fmaxf(sx, EPSf);
                float iy = 0.5f / (sby * sby), ix = 0.5f / (sbx * sbx);

                unsigned sm = 0;
#pragma unroll
                for (int k = 0; k < Kdim; ++k) {
                    float dy = ey - cky[k];
                    float dx = ex - ckx[k];
                    float q = fmaf(dy * dy, iy, dx * dx * ix);
                    if (q < QCLIP) sm |= (1u << k);
                }
                int ow = (own >= 0) ? own : 16;
                float4 mw = msw_s[ow];
                float devv = fabsf(sy - mw.x) + fabsf(sx - mw.y);
                varsum = fmaf(devv, mw.z, varsum);

                float st = (own >= 0) ? EPSf : 0.f;
                while (sm) {  // rare slow path: near some center
                    int k = __ffs(sm) - 1;
                    sm &= sm - 1;
                    float dy = ey - ck_s[k * 2];
                    float dx = ex - ck_s[k * 2 + 1];
                    float q = fmaf(dy * dy, iy, dx * dx * ix);
                    float phi = expf(-q);
                    phi = fminf(fmaxf(phi, EPSf), 1.0f - EPSf);
                    float lg = logf(phi) - log1pf(-phi);
                    bool isPos = (k == own);
                    float e;
                    if (isPos) {
                        st = phi;
                        atomicAdd(&posnh[b * Kdim + k], 1u);
                        e = 1.0f - lg;
                    } else {
                        e = 1.0f + lg;
                    }
                    if (e > 0.f) {
                        int bin = (int)(e * INV_BIN_W);
                        if (bin > NBINS - 1) bin = NBINS - 1;
                        atomicAdd(&hb[(k * 2 + (isPos ? 1 : 0)) * NBINS + bin], 1u);
                    }
                }
                float dd = sea[j] - st;
                ssum = fmaf(dd, dd, ssum);
            }
        }
        if (p < 2) {
            coy = noy; cox = nox; csy = nsy; csx = nsx; cse = nse; ct = nt_;
            g += GPI;
        }
    }

#pragma unroll
    for (int o = 32; o >= 1; o >>= 1) {
        varsum += __shfl_xor(varsum, o);
        ssum += __shfl_xor(ssum, o);
    }
    if (lane == 0) {
        part[wv][0] = varsum;
        part[wv][1] = ssum;
    }
    __syncthreads();
    if (threadIdx.x < 2) {
        float v = part[0][threadIdx.x] + part[1][threadIdx.x] +
                  part[2][threadIdx.x] + part[3][threadIdx.x];
        ws[MPART_OFF + (size_t)(b * NSB + blockIdx.x) * 2 + threadIdx.x] = v;
    }
}

// One wave per (b,k): suffix-scan histogram top-down, trapezoid-integrate.
// Last block to finish also does the final combine (counter in hist[NHIST+64]).
__global__ void k_lovasz(float* __restrict__ ws, unsigned* __restrict__ hist,
                         float* __restrict__ out) {
    int i = blockIdx.x;  // 0..63
    int lane = threadIdx.x;
    float P = ws[ACC_OFF + i * 5];
    float res = 0.f;
    if (P >= 0.5f) {
        const unsigned* hn = hist + (size_t)i * 2 * NBINS;
        const unsigned* hp = hn + NBINS;
        const unsigned* posnh = hist + (size_t)NHIST;
        const float C_LO = logf(EPSf) - log1pf(-EPSf);
        const int HOTBIN = (int)((1.0f - C_LO) * INV_BIN_W);
        int deficit = (int)(P + 0.5f) - (int)posnh[i];
        int carry_p = 0, carry_n = 0;
        float Jtop = 0.f;
        float trap = 0.f;
        for (int c = NBINS / 64 - 1; c >= 0; --c) {
            int m = c * 64 + lane;
            int vp = (int)hp[m];
            int vn = (int)hn[m];
            if (m == HOTBIN) vp += deficit;
            for (int o = 1; o < 64; o <<= 1) {
                int tp = __shfl_down(vp, o);
                int tn = __shfl_down(vn, o);
                if (lane + o < 64) { vp += tp; vn += tn; }
            }
            float p_edge = (float)(carry_p + vp);
            float n_edge = (float)(carry_n + vn);
            float J = 1.0f - (P - p_edge) / (P + n_edge);
            float Jn = __shfl_down(J, 1);
            if (lane == 63) Jn = Jtop;
            trap += 0.5f * (J + Jn);
            carry_p += __shfl(vp, 0);
            carry_n += __shfl(vn, 0);
            Jtop = __shfl(J, 0);
        }
        for (int o = 1; o < 64; o <<= 1) {
            float t2 = __shfl_down(trap, o);
            if (lane + o < 64) trap += t2;
        }
        res = trap * BIN_W;
    }
    if (lane == 0) ws[LOVARR_OFF + i] = res;
    __threadfence();

    // completion counter: last block does the final combine
    __shared__ unsigned ticket;
    if (lane == 0) ticket = atomicAdd(&hist[NHIST + 64], 1u);
    __syncthreads();
    if (ticket != 63u) return;

    float v = 0.f, s = 0.f, l = 0.f, pr = 0.f;
    for (int j = lane; j < NBLK; j += 64) {
        v += ws[MPART_OFF + 2 * j];
        s += ws[MPART_OFF + 2 * j + 1];
    }
    l = ws[LOVARR_OFF + lane];
    pr = (ws[ACC_OFF + lane * 5] > 0.f) ? 1.f : 0.f;
#pragma unroll
    for (int o = 32; o >= 1; o >>= 1) {
        v += __shfl_xor(v, o);
        s += __shfl_xor(s, o);
        l += __shfl_xor(l, o);
        pr += __shfl_xor(pr, o);
    }
    if (lane == 0) {
        float npres = fmaxf(pr, 1.0f);
        out[0] = l / npres + 10.0f * (v / npres) +
                 s / (float)((size_t)Bdim * HWPIX);
    }
}

extern "C" void kernel_launch(void* const* d_in, const int* in_sizes, int n_in,
                              void* d_out, int out_size, void* d_ws, size_t ws_size,
                              hipStream_t stream) {
    const float* yp = (const float*)d_in[0];
    const int* yt = (const int*)d_in[1];
    float* ws = (float*)d_ws;
    unsigned* hist = (unsigned*)((char*)d_ws + HIST_OFF_F * 4);

    dim3 g(NSB, Bdim);
    k_stats<<<g, 256, 0, stream>>>(yp, yt, ws, hist);
    k_centers2<<<80, 256, 0, stream>>>(ws);
    k_main<<<g, 256, 0, stream>>>(yp, yt, ws, hist);
    k_lovasz<<<64, 64, 0, stream>>>(ws, hist, (float*)d_out);
}